// Round 8
// baseline (368.289 us; speedup 1.0000x reference)
//
#include <hip/hip_runtime.h>
#include <hip/hip_bf16.h>

// C[M,N] = A[M,K] @ W[N,K]^T ; M=32768, N=K=2048. fp32 in/out.
// R8: R7 skeleton (256x256 tile, 8 waves, 1 barrier/K-tile, gload_lds staging
// with pre-swizzled source) but MFMA shape 32x32x16 (ceiling 2382-2495 TF vs
// 2075 for 16x16x32; half the MFMA instruction count, same LDS read count).
// Per wave: output 128x64 = 4 m-tiles(32r) x 2 n-tiles(32c); BK=64 = 4 ksteps.
// Frag layout: A row=lane&31, k=(lane>>5)*8+e (generalization of the
// R1-R7-validated 16x16 pattern); C/D col=lane&31,
// row=(reg&3)+8*(reg>>2)+4*(lane>>5)  [m74/m101-verified].

typedef __attribute__((ext_vector_type(8))) short bf16x8;
typedef __attribute__((ext_vector_type(4))) float f32x4;
typedef __attribute__((ext_vector_type(16))) float f32x16;

#define M_DIM 32768
#define N_DIM 2048
#define K_DIM 2048
#define BM 256
#define BN 256
#define BK 64
#define NT (K_DIM / BK)              // 32
#define NBN (N_DIM / BN)             // 8
#define NWG ((M_DIM / BM) * NBN)     // 1024

typedef __attribute__((address_space(3))) char lds_char;
typedef __attribute__((address_space(1))) char glb_char;

__device__ __forceinline__ unsigned short f2bf(float f) {
    __bf16 b = (__bf16)f;   // RNE
    return __builtin_bit_cast(unsigned short, b);
}

// ---------------- fp32 -> bf16 convert (memory-bound, grid-stride) ----------
__global__ __launch_bounds__(256)
void cvt_f32_bf16(const float* __restrict__ src, ushort* __restrict__ dst, int n8) {
    const float4* s4 = (const float4*)src;
    int idx = blockIdx.x * blockDim.x + threadIdx.x;
    int stride = gridDim.x * blockDim.x;
    for (int i = idx; i < n8; i += stride) {
        float4 a = s4[2 * (size_t)i];
        float4 b = s4[2 * (size_t)i + 1];
        ushort r[8] = {f2bf(a.x), f2bf(a.y), f2bf(a.z), f2bf(a.w),
                       f2bf(b.x), f2bf(b.y), f2bf(b.z), f2bf(b.w)};
        *reinterpret_cast<uint4*>(dst + 8 * (size_t)i) =
            *reinterpret_cast<const uint4*>(r);
    }
}

// ---------------- 256^2 8-wave, 32x32x16-MFMA bf16 GEMM ---------------------
__global__ __launch_bounds__(512, 2)
void agmm_32x32(const ushort* __restrict__ A, const ushort* __restrict__ W,
                float* __restrict__ C) {
    // sA[buf]: buf*32768 ; sB[buf]: 65536 + buf*32768 (256r x 64c bf16, 128B rows)
    __shared__ __attribute__((aligned(16))) char sm[131072];

    const int tid  = threadIdx.x;
    const int lane = tid & 63;
    const int w    = tid >> 6;      // 0..7
    const int wm   = w >> 2;        // 0..1 -> 128-row half of A tile
    const int wn   = w & 3;         // 0..3 -> 64-col slice of B tile

    const int bid = blockIdx.x;
    const int swz = (bid & 7) * (NWG / 8) + (bid >> 3);  // bijective (NWG%8==0)
    const int bm  = swz >> 3;            // 0..127
    const int bn  = swz & (NBN - 1);     // 0..7

    // staging source pre-swizzle (linear LDS dest; read applies same XOR)
    const int lsub = lane >> 3;                       // row&7 at dest
    const int scol = ((lane & 7) ^ lsub) << 3;        // pre-swizzled col elems

    const ushort* Abase = A + (size_t)bm * BM * K_DIM + scol;
    const ushort* Wbase = W + (size_t)bn * BN * K_DIM + scol;

    // 32x32 fragment read constants
    const int r5   = lane & 31;           // row within 32-row tile
    const int h    = lane >> 5;           // k-half (0/1)
    const int fx32 = (r5 & 7) << 4;       // read-side swizzle (row&7 == r5&7)
    // k byte offsets per kstep s: (s*32 + h*16) ^ fx32
    const int ko0 = (0 * 32 + h * 16) ^ fx32;
    const int ko1 = (1 * 32 + h * 16) ^ fx32;
    const int ko2 = (2 * 32 + h * 16) ^ fx32;
    const int ko3 = (3 * 32 + h * 16) ^ fx32;

    const int abC = (wm * 128 + r5) * 128;             // A row base (buf0)
    const int bbC = 65536 + (wn * 64 + r5) * 128;      // B row base (buf0)

    f32x16 acc[4][2];
#pragma unroll
    for (int mt = 0; mt < 4; ++mt)
#pragma unroll
        for (int nt = 0; nt < 2; ++nt)
#pragma unroll
            for (int j = 0; j < 16; ++j)
                acc[mt][nt][j] = 0.f;

    bf16x8 afA[4], afB[4];   // double-banked A frags (4 ksteps each)
    bf16x8 bfr[2][4];        // B frags, live for whole K-tile

#define GLD16(SRC, LOFF)                                                       \
    __builtin_amdgcn_global_load_lds((const glb_char*)(SRC),                   \
                                     (lds_char*)(sm + (LOFF)), 16, 0, 0)
    // stage FULL A tile (256 rows): 4 loads/wave; wave w covers rows 16w..16w+15
#define STAGE_A2(KT, BUF) do {                                                 \
        const int ra_ = (w << 4);                                              \
        GLD16(Abase + (size_t)(ra_ + lsub) * K_DIM + (KT) * BK,                \
              (BUF) * 32768 + ra_ * 128);                                      \
        GLD16(Abase + (size_t)(ra_ + 8 + lsub) * K_DIM + (KT) * BK,            \
              (BUF) * 32768 + (ra_ + 8) * 128);                                \
        GLD16(Abase + (size_t)(128 + ra_ + lsub) * K_DIM + (KT) * BK,          \
              (BUF) * 32768 + (128 + ra_) * 128);                              \
        GLD16(Abase + (size_t)(128 + ra_ + 8 + lsub) * K_DIM + (KT) * BK,      \
              (BUF) * 32768 + (128 + ra_ + 8) * 128);                          \
    } while (0)
    // stage one B half-tile (128 rows): 2 loads/wave
#define STAGE_B(KT, H, BUF) do {                                               \
        const int rb_ = (H) * 128 + (w << 4);                                  \
        GLD16(Wbase + (size_t)(rb_ + lsub) * K_DIM + (KT) * BK,                \
              65536 + (BUF) * 32768 + rb_ * 128);                              \
        GLD16(Wbase + (size_t)(rb_ + 8 + lsub) * K_DIM + (KT) * BK,            \
              65536 + (BUF) * 32768 + (rb_ + 8) * 128);                        \
    } while (0)

    // read A m-tile MT's 4 kstep frags into DST
#define RD_A(MT, ABASE, DST) do {                                              \
        const int rb_ = (ABASE) + (MT) * 32 * 128;                             \
        DST[0] = *(const bf16x8*)(sm + rb_ + ko0);                             \
        DST[1] = *(const bf16x8*)(sm + rb_ + ko1);                             \
        DST[2] = *(const bf16x8*)(sm + rb_ + ko2);                             \
        DST[3] = *(const bf16x8*)(sm + rb_ + ko3);                             \
    } while (0)
#define RD_B(BBASE) do {                                                       \
        _Pragma("unroll") for (int nt = 0; nt < 2; ++nt) {                     \
            const int rb_ = (BBASE) + nt * 32 * 128;                           \
            bfr[nt][0] = *(const bf16x8*)(sm + rb_ + ko0);                     \
            bfr[nt][1] = *(const bf16x8*)(sm + rb_ + ko1);                     \
            bfr[nt][2] = *(const bf16x8*)(sm + rb_ + ko2);                     \
            bfr[nt][3] = *(const bf16x8*)(sm + rb_ + ko3);                     \
        }                                                                      \
    } while (0)
    // 8 MFMA for m-tile MT (s outer, nt inner -> dep distance 2)
#define MFMA_T(MT, AF) do {                                                    \
        __builtin_amdgcn_s_setprio(1);                                         \
        _Pragma("unroll") for (int s = 0; s < 4; ++s)                          \
        _Pragma("unroll") for (int nt = 0; nt < 2; ++nt)                       \
            acc[MT][nt] = __builtin_amdgcn_mfma_f32_32x32x16_bf16(             \
                AF[s], bfr[nt][s], acc[MT][nt], 0, 0, 0);                      \
        __builtin_amdgcn_s_setprio(0);                                         \
    } while (0)

#define TILE_BOUNDARY do {                                                     \
        asm volatile("s_waitcnt vmcnt(0)" ::: "memory");                       \
        __builtin_amdgcn_s_barrier();                                          \
        __builtin_amdgcn_sched_barrier(0);                                     \
    } while (0)

    // prologue: stage tile 0 into buf0 (8 loads), publish
    STAGE_A2(0, 0);
    STAGE_B(0, 0, 0);
    STAGE_B(0, 1, 0);
    TILE_BOUNDARY;

    for (int t = 0; t < NT - 1; ++t) {
        const int cur   = t & 1;
        const int nxt   = cur ^ 1;
        const int abase = cur * 32768 + abC;
        const int bbase = cur * 32768 + bbC;
        RD_B(bbase);
        RD_A(0, abase, afA);
        RD_A(1, abase, afB);
        STAGE_A2(t + 1, nxt);
        MFMA_T(0, afA);
        RD_A(2, abase, afA);
        STAGE_B(t + 1, 0, nxt);
        MFMA_T(1, afB);
        RD_A(3, abase, afB);
        STAGE_B(t + 1, 1, nxt);
        MFMA_T(2, afA);
        MFMA_T(3, afB);
        TILE_BOUNDARY;   // pre-aged drain of the 8 stage loads + publish
    }
    {   // last tile (buf parity 1): no staging, no trailing barrier
        const int abase = 32768 + abC;
        const int bbase = 32768 + bbC;
        RD_B(bbase);
        RD_A(0, abase, afA);
        RD_A(1, abase, afB);
        MFMA_T(0, afA);
        RD_A(2, abase, afA);
        MFMA_T(1, afB);
        RD_A(3, abase, afB);
        MFMA_T(2, afA);
        MFMA_T(3, afB);
    }
#undef TILE_BOUNDARY
#undef MFMA_T
#undef RD_B
#undef RD_A
#undef STAGE_B
#undef STAGE_A2
#undef GLD16

    // epilogue: 32x32 C/D map col=lane&31, row=(j&3)+8*(j>>2)+4*(lane>>5)
    const size_t crow0 = (size_t)(bm * BM + wm * 128 + 4 * h);
    const int    ccol0 = bn * BN + wn * 64 + r5;
    float* Cp = C + crow0 * N_DIM + ccol0;
#pragma unroll
    for (int mt = 0; mt < 4; ++mt)
#pragma unroll
        for (int j = 0; j < 16; ++j) {
            float* cr = Cp + (size_t)(mt * 32 + (j & 3) + 8 * (j >> 2)) * N_DIM;
#pragma unroll
            for (int nt = 0; nt < 2; ++nt)
                cr[nt * 32] = acc[mt][nt][j];
        }
}

// ---------------- fused fp32 fallback (ws too small; R1-validated) ----------
__global__ __launch_bounds__(256, 2)
void agmm_fused(const float* __restrict__ A, const float* __restrict__ W,
                float* __restrict__ C) {
    __shared__ __attribute__((aligned(16))) char sA[128 * 64 * 2];
    __shared__ __attribute__((aligned(16))) char sB[128 * 64 * 2];

    const int tid  = threadIdx.x;
    const int lane = tid & 63;
    const int wid  = tid >> 6;
    const int wm   = wid >> 1;
    const int wn   = wid & 1;

    const int nwg = (M_DIM / 128) * (N_DIM / 128);
    const int bid = blockIdx.x;
    const int swz = (bid & 7) * (nwg / 8) + (bid >> 3);
    const int bm  = swz >> 4;
    const int bn  = swz & 15;

    const int srow = tid >> 4;
    const int scol = (tid & 15) << 2;

    const float* Ap = A + (size_t)(bm * 128 + srow) * K_DIM + scol;
    const float* Wp = W + (size_t)(bn * 128 + srow) * K_DIM + scol;
    const int wbase = (srow * 128 + (scol << 1)) ^ ((srow & 7) << 4);

    const int lrow = lane & 15;
    const int lkb  = (lane >> 4) << 3;
    const int fxor = (lrow & 7) << 4;
    const int arow0 = (wm * 64 + lrow) * 128;
    const int brow0 = (wn * 64 + lrow) * 128;

    f32x4 acc[4][4];
#pragma unroll
    for (int m = 0; m < 4; ++m)
#pragma unroll
        for (int n = 0; n < 4; ++n)
            acc[m][n] = (f32x4){0.f, 0.f, 0.f, 0.f};

    float4 areg[8], breg[8];
#pragma unroll
    for (int p = 0; p < 8; ++p) {
        areg[p] = *reinterpret_cast<const float4*>(Ap + (size_t)p * 16 * K_DIM);
        breg[p] = *reinterpret_cast<const float4*>(Wp + (size_t)p * 16 * K_DIM);
    }

    for (int kt = 0; kt < NT; ++kt) {
        __syncthreads();
#pragma unroll
        for (int p = 0; p < 8; ++p) {
            ushort av[4] = {f2bf(areg[p].x), f2bf(areg[p].y),
                            f2bf(areg[p].z), f2bf(areg[p].w)};
            *reinterpret_cast<ushort4*>(sA + (wbase + p * 2048)) =
                *reinterpret_cast<ushort4*>(av);
            ushort bv[4] = {f2bf(breg[p].x), f2bf(breg[p].y),
                            f2bf(breg[p].z), f2bf(breg[p].w)};
            *reinterpret_cast<ushort4*>(sB + (wbase + p * 2048)) =
                *reinterpret_cast<ushort4*>(bv);
        }
        __syncthreads();

        if (kt + 1 < NT) {
            const float* ap = Ap + (size_t)(kt + 1) * BK;
            const float* wp = Wp + (size_t)(kt + 1) * BK;
#pragma unroll
            for (int p = 0; p < 8; ++p) {
                areg[p] = *reinterpret_cast<const float4*>(ap + (size_t)p * 16 * K_DIM);
                breg[p] = *reinterpret_cast<const float4*>(wp + (size_t)p * 16 * K_DIM);
            }
        }

#pragma unroll
        for (int kk = 0; kk < 2; ++kk) {
            const int kcb = (kk * 32 + lkb) * 2;
            bf16x8 af[4], bfv[4];
#pragma unroll
            for (int m = 0; m < 4; ++m)
                af[m] = *reinterpret_cast<const bf16x8*>(
                    sA + ((arow0 + m * 2048 + kcb) ^ fxor));
#pragma unroll
            for (int n = 0; n < 4; ++n)
                bfv[n] = *reinterpret_cast<const bf16x8*>(
                    sB + ((brow0 + n * 2048 + kcb) ^ fxor));
#pragma unroll
            for (int m = 0; m < 4; ++m)
#pragma unroll
                for (int n = 0; n < 4; ++n)
                    acc[m][n] = __builtin_amdgcn_mfma_f32_16x16x32_bf16(
                        af[m], bfv[n], acc[m][n], 0, 0, 0);
        }
    }

    const size_t crow = (size_t)(bm * 128 + wm * 64 + ((lane >> 4) << 2));
    const int    ccol = bn * 128 + wn * 64 + (lane & 15);
    float* Cp = C + crow * N_DIM + ccol;
#pragma unroll
    for (int m = 0; m < 4; ++m)
#pragma unroll
        for (int j = 0; j < 4; ++j) {
            float* cr = Cp + (size_t)(m * 16 + j) * N_DIM;
#pragma unroll
            for (int n = 0; n < 4; ++n)
                cr[n * 16] = acc[m][n][j];
        }
}

extern "C" void kernel_launch(void* const* d_in, const int* in_sizes, int n_in,
                              void* d_out, int out_size, void* d_ws, size_t ws_size,
                              hipStream_t stream) {
    const float* A  = (const float*)d_in[0];   // [8,4096,2048] fp32
    const float* Wt = (const float*)d_in[1];   // [2048,2048] fp32
    float* C = (float*)d_out;                  // [32768,2048] fp32

    const size_t needA = (size_t)M_DIM * K_DIM * 2;
    const size_t needW = (size_t)N_DIM * K_DIM * 2;

    if (ws_size >= needA + needW) {
        ushort* Abf = (ushort*)d_ws;
        ushort* Wbf = (ushort*)((char*)d_ws + needA);
        cvt_f32_bf16<<<dim3(2048), dim3(256), 0, stream>>>(A, Abf, (M_DIM * K_DIM) / 8);
        cvt_f32_bf16<<<dim3(2048), dim3(256), 0, stream>>>(Wt, Wbf, (N_DIM * K_DIM) / 8);
        agmm_32x32<<<dim3(NWG), dim3(512), 0, stream>>>(Abf, Wbf, C);
    } else {
        agmm_fused<<<dim3((M_DIM / 128) * (N_DIM / 128)), dim3(256), 0, stream>>>(A, Wt, C);
    }
}

// Round 9
// 362.510 us; speedup vs baseline: 1.0159x; 1.0159x over previous
//
#include <hip/hip_runtime.h>
#include <hip/hip_bf16.h>

// C[M,N] = A[M,K] @ W[N,K]^T ; M=32768, N=K=2048. fp32 in/out.
// R9: R8 (32x32x16 MFMA on R7 skeleton) + WIDENED swizzle to fix R8's 2.5e7
// bank conflicts. Slot function now  slot = col ^ (row&7) ^ ((row>>3)&3)
// (row bits [4:3] added): bijective per 32-row span, so the 32x32 fragment
// read (32 lanes x same logical col) spreads 2-per-slot per 16-lane subgroup.
// Applied identically on staging source (per-8-row-block XOR g=(R0>>3)&3,
// uniform per gload_lds since all blocks are 8-row aligned) and on reads
// (fx32 = ((r5&7)^((r5>>3)&3))<<4). Rule #21: same involution both sides.

typedef __attribute__((ext_vector_type(8))) short bf16x8;
typedef __attribute__((ext_vector_type(4))) float f32x4;
typedef __attribute__((ext_vector_type(16))) float f32x16;

#define M_DIM 32768
#define N_DIM 2048
#define K_DIM 2048
#define BM 256
#define BN 256
#define BK 64
#define NT (K_DIM / BK)              // 32
#define NBN (N_DIM / BN)             // 8
#define NWG ((M_DIM / BM) * NBN)     // 1024

typedef __attribute__((address_space(3))) char lds_char;
typedef __attribute__((address_space(1))) char glb_char;

__device__ __forceinline__ unsigned short f2bf(float f) {
    __bf16 b = (__bf16)f;   // RNE
    return __builtin_bit_cast(unsigned short, b);
}

// ---------------- fp32 -> bf16 convert (memory-bound, grid-stride) ----------
__global__ __launch_bounds__(256)
void cvt_f32_bf16(const float* __restrict__ src, ushort* __restrict__ dst, int n8) {
    const float4* s4 = (const float4*)src;
    int idx = blockIdx.x * blockDim.x + threadIdx.x;
    int stride = gridDim.x * blockDim.x;
    for (int i = idx; i < n8; i += stride) {
        float4 a = s4[2 * (size_t)i];
        float4 b = s4[2 * (size_t)i + 1];
        ushort r[8] = {f2bf(a.x), f2bf(a.y), f2bf(a.z), f2bf(a.w),
                       f2bf(b.x), f2bf(b.y), f2bf(b.z), f2bf(b.w)};
        *reinterpret_cast<uint4*>(dst + 8 * (size_t)i) =
            *reinterpret_cast<const uint4*>(r);
    }
}

// ---------------- 256^2 8-wave, 32x32x16-MFMA bf16 GEMM ---------------------
__global__ __launch_bounds__(512, 2)
void agmm_32swz(const ushort* __restrict__ A, const ushort* __restrict__ W,
                float* __restrict__ C) {
    // sA[buf]: buf*32768 ; sB[buf]: 65536 + buf*32768 (256r x 64c bf16, 128B rows)
    __shared__ __attribute__((aligned(16))) char sm[131072];

    const int tid  = threadIdx.x;
    const int lane = tid & 63;
    const int w    = tid >> 6;      // 0..7
    const int wm   = w >> 2;        // 0..1 -> 128-row half of A tile
    const int wn   = w & 3;         // 0..3 -> 64-col slice of B tile

    const int bid = blockIdx.x;
    const int swz = (bid & 7) * (NWG / 8) + (bid >> 3);  // bijective (NWG%8==0)
    const int bm  = swz >> 3;            // 0..127
    const int bn  = swz & (NBN - 1);     // 0..7

    const int lsub = lane >> 3;          // row&7 at LDS dest for staging
    const int l7   = lane & 7;

    const ushort* Abase = A + (size_t)bm * BM * K_DIM;
    const ushort* Wbase = W + (size_t)bn * BN * K_DIM;

    // 32x32 fragment read constants
    const int r5   = lane & 31;           // row within 32-row tile
    const int h    = lane >> 5;           // k-half (0/1)
    const int fx32 = (((r5 & 7) ^ ((r5 >> 3) & 3)) << 4);   // widened swizzle
    const int ko0 = (0 * 32 + h * 16) ^ fx32;
    const int ko1 = (1 * 32 + h * 16) ^ fx32;
    const int ko2 = (2 * 32 + h * 16) ^ fx32;
    const int ko3 = (3 * 32 + h * 16) ^ fx32;

    const int abC = (wm * 128 + r5) * 128;             // A row base (buf0)
    const int bbC = 65536 + (wn * 64 + r5) * 128;      // B row base (buf0)

    f32x16 acc[4][2];
#pragma unroll
    for (int mt = 0; mt < 4; ++mt)
#pragma unroll
        for (int nt = 0; nt < 2; ++nt)
#pragma unroll
            for (int j = 0; j < 16; ++j)
                acc[mt][nt][j] = 0.f;

    bf16x8 afA[4], afB[4];   // double-banked A frags (4 ksteps each)
    bf16x8 bfr[2][4];        // B frags, live for whole K-tile

#define GLD16(SRC, LOFF)                                                       \
    __builtin_amdgcn_global_load_lds((const glb_char*)(SRC),                   \
                                     (lds_char*)(sm + (LOFF)), 16, 0, 0)
    // one 8-row block (R0 multiple of 8): source col pre-swizzled by
    // chunk = l7 ^ lsub ^ ((R0>>3)&3); dest linear.
#define GLDA(R0, KT, BUF) do {                                                 \
        const int g_ = ((R0) >> 3) & 3;                                        \
        GLD16(Abase + (size_t)((R0) + lsub) * K_DIM + (KT) * BK +              \
                  ((l7 ^ lsub ^ g_) << 3),                                     \
              (BUF) * 32768 + (R0) * 128);                                     \
    } while (0)
#define GLDB(R0, KT, BUF) do {                                                 \
        const int g_ = ((R0) >> 3) & 3;                                        \
        GLD16(Wbase + (size_t)((R0) + lsub) * K_DIM + (KT) * BK +              \
                  ((l7 ^ lsub ^ g_) << 3),                                     \
              65536 + (BUF) * 32768 + (R0) * 128);                             \
    } while (0)
    // stage FULL A tile (256 rows): 4 blocks/wave
#define STAGE_A2(KT, BUF) do {                                                 \
        GLDA((w << 4), KT, BUF);                                               \
        GLDA((w << 4) + 8, KT, BUF);                                           \
        GLDA(128 + (w << 4), KT, BUF);                                         \
        GLDA(128 + (w << 4) + 8, KT, BUF);                                     \
    } while (0)
    // stage one B half-tile (128 rows): 2 blocks/wave
#define STAGE_B(KT, H, BUF) do {                                               \
        GLDB((H) * 128 + (w << 4), KT, BUF);                                   \
        GLDB((H) * 128 + (w << 4) + 8, KT, BUF);                               \
    } while (0)

    // read A m-tile MT's 4 kstep frags into DST
#define RD_A(MT, ABASE, DST) do {                                              \
        const int rb_ = (ABASE) + (MT) * 32 * 128;                             \
        DST[0] = *(const bf16x8*)(sm + rb_ + ko0);                             \
        DST[1] = *(const bf16x8*)(sm + rb_ + ko1);                             \
        DST[2] = *(const bf16x8*)(sm + rb_ + ko2);                             \
        DST[3] = *(const bf16x8*)(sm + rb_ + ko3);                             \
    } while (0)
#define RD_B(BBASE) do {                                                       \
        _Pragma("unroll") for (int nt = 0; nt < 2; ++nt) {                     \
            const int rb_ = (BBASE) + nt * 32 * 128;                           \
            bfr[nt][0] = *(const bf16x8*)(sm + rb_ + ko0);                     \
            bfr[nt][1] = *(const bf16x8*)(sm + rb_ + ko1);                     \
            bfr[nt][2] = *(const bf16x8*)(sm + rb_ + ko2);                     \
            bfr[nt][3] = *(const bf16x8*)(sm + rb_ + ko3);                     \
        }                                                                      \
    } while (0)
#define MFMA_T(MT, AF) do {                                                    \
        __builtin_amdgcn_s_setprio(1);                                         \
        _Pragma("unroll") for (int s = 0; s < 4; ++s)                          \
        _Pragma("unroll") for (int nt = 0; nt < 2; ++nt)                       \
            acc[MT][nt] = __builtin_amdgcn_mfma_f32_32x32x16_bf16(             \
                AF[s], bfr[nt][s], acc[MT][nt], 0, 0, 0);                      \
        __builtin_amdgcn_s_setprio(0);                                         \
    } while (0)

#define TILE_BOUNDARY do {                                                     \
        asm volatile("s_waitcnt vmcnt(0)" ::: "memory");                       \
        __builtin_amdgcn_s_barrier();                                          \
        __builtin_amdgcn_sched_barrier(0);                                     \
    } while (0)

    // prologue: stage tile 0 into buf0 (8 loads), publish
    STAGE_A2(0, 0);
    STAGE_B(0, 0, 0);
    STAGE_B(0, 1, 0);
    TILE_BOUNDARY;

    for (int t = 0; t < NT - 1; ++t) {
        const int cur   = t & 1;
        const int nxt   = cur ^ 1;
        const int abase = cur * 32768 + abC;
        const int bbase = cur * 32768 + bbC;
        RD_B(bbase);
        RD_A(0, abase, afA);
        RD_A(1, abase, afB);
        STAGE_A2(t + 1, nxt);
        MFMA_T(0, afA);
        RD_A(2, abase, afA);
        STAGE_B(t + 1, 0, nxt);
        MFMA_T(1, afB);
        RD_A(3, abase, afB);
        STAGE_B(t + 1, 1, nxt);
        MFMA_T(2, afA);
        MFMA_T(3, afB);
        TILE_BOUNDARY;   // pre-aged drain of the 8 stage loads + publish
    }
    {   // last tile (buf parity 1): no staging, no trailing barrier
        const int abase = 32768 + abC;
        const int bbase = 32768 + bbC;
        RD_B(bbase);
        RD_A(0, abase, afA);
        RD_A(1, abase, afB);
        MFMA_T(0, afA);
        RD_A(2, abase, afA);
        MFMA_T(1, afB);
        RD_A(3, abase, afB);
        MFMA_T(2, afA);
        MFMA_T(3, afB);
    }
#undef TILE_BOUNDARY
#undef MFMA_T
#undef RD_B
#undef RD_A
#undef STAGE_B
#undef STAGE_A2
#undef GLDB
#undef GLDA
#undef GLD16

    // epilogue: 32x32 C/D map col=lane&31, row=(j&3)+8*(j>>2)+4*(lane>>5)
    const size_t crow0 = (size_t)(bm * BM + wm * 128 + 4 * h);
    const int    ccol0 = bn * BN + wn * 64 + r5;
    float* Cp = C + crow0 * N_DIM + ccol0;
#pragma unroll
    for (int mt = 0; mt < 4; ++mt)
#pragma unroll
        for (int j = 0; j < 16; ++j) {
            float* cr = Cp + (size_t)(mt * 32 + (j & 3) + 8 * (j >> 2)) * N_DIM;
#pragma unroll
            for (int nt = 0; nt < 2; ++nt)
                cr[nt * 32] = acc[mt][nt][j];
        }
}

// ---------------- fused fp32 fallback (ws too small; R1-validated) ----------
__global__ __launch_bounds__(256, 2)
void agmm_fused(const float* __restrict__ A, const float* __restrict__ W,
                float* __restrict__ C) {
    __shared__ __attribute__((aligned(16))) char sA[128 * 64 * 2];
    __shared__ __attribute__((aligned(16))) char sB[128 * 64 * 2];

    const int tid  = threadIdx.x;
    const int lane = tid & 63;
    const int wid  = tid >> 6;
    const int wm   = wid >> 1;
    const int wn   = wid & 1;

    const int nwg = (M_DIM / 128) * (N_DIM / 128);
    const int bid = blockIdx.x;
    const int swz = (bid & 7) * (nwg / 8) + (bid >> 3);
    const int bm  = swz >> 4;
    const int bn  = swz & 15;

    const int srow = tid >> 4;
    const int scol = (tid & 15) << 2;

    const float* Ap = A + (size_t)(bm * 128 + srow) * K_DIM + scol;
    const float* Wp = W + (size_t)(bn * 128 + srow) * K_DIM + scol;
    const int wbase = (srow * 128 + (scol << 1)) ^ ((srow & 7) << 4);

    const int lrow = lane & 15;
    const int lkb  = (lane >> 4) << 3;
    const int fxor = (lrow & 7) << 4;
    const int arow0 = (wm * 64 + lrow) * 128;
    const int brow0 = (wn * 64 + lrow) * 128;

    f32x4 acc[4][4];
#pragma unroll
    for (int m = 0; m < 4; ++m)
#pragma unroll
        for (int n = 0; n < 4; ++n)
            acc[m][n] = (f32x4){0.f, 0.f, 0.f, 0.f};

    float4 areg[8], breg[8];
#pragma unroll
    for (int p = 0; p < 8; ++p) {
        areg[p] = *reinterpret_cast<const float4*>(Ap + (size_t)p * 16 * K_DIM);
        breg[p] = *reinterpret_cast<const float4*>(Wp + (size_t)p * 16 * K_DIM);
    }

    for (int kt = 0; kt < NT; ++kt) {
        __syncthreads();
#pragma unroll
        for (int p = 0; p < 8; ++p) {
            ushort av[4] = {f2bf(areg[p].x), f2bf(areg[p].y),
                            f2bf(areg[p].z), f2bf(areg[p].w)};
            *reinterpret_cast<ushort4*>(sA + (wbase + p * 2048)) =
                *reinterpret_cast<ushort4*>(av);
            ushort bv[4] = {f2bf(breg[p].x), f2bf(breg[p].y),
                            f2bf(breg[p].z), f2bf(breg[p].w)};
            *reinterpret_cast<ushort4*>(sB + (wbase + p * 2048)) =
                *reinterpret_cast<ushort4*>(bv);
        }
        __syncthreads();

        if (kt + 1 < NT) {
            const float* ap = Ap + (size_t)(kt + 1) * BK;
            const float* wp = Wp + (size_t)(kt + 1) * BK;
#pragma unroll
            for (int p = 0; p < 8; ++p) {
                areg[p] = *reinterpret_cast<const float4*>(ap + (size_t)p * 16 * K_DIM);
                breg[p] = *reinterpret_cast<const float4*>(wp + (size_t)p * 16 * K_DIM);
            }
        }

#pragma unroll
        for (int kk = 0; kk < 2; ++kk) {
            const int kcb = (kk * 32 + lkb) * 2;
            bf16x8 af[4], bfv[4];
#pragma unroll
            for (int m = 0; m < 4; ++m)
                af[m] = *reinterpret_cast<const bf16x8*>(
                    sA + ((arow0 + m * 2048 + kcb) ^ fxor));
#pragma unroll
            for (int n = 0; n < 4; ++n)
                bfv[n] = *reinterpret_cast<const bf16x8*>(
                    sB + ((brow0 + n * 2048 + kcb) ^ fxor));
#pragma unroll
            for (int m = 0; m < 4; ++m)
#pragma unroll
                for (int n = 0; n < 4; ++n)
                    acc[m][n] = __builtin_amdgcn_mfma_f32_16x16x32_bf16(
                        af[m], bfv[n], acc[m][n], 0, 0, 0);
        }
    }

    const size_t crow = (size_t)(bm * 128 + wm * 64 + ((lane >> 4) << 2));
    const int    ccol = bn * 128 + wn * 64 + (lane & 15);
    float* Cp = C + crow * N_DIM + ccol;
#pragma unroll
    for (int m = 0; m < 4; ++m)
#pragma unroll
        for (int j = 0; j < 4; ++j) {
            float* cr = Cp + (size_t)(m * 16 + j) * N_DIM;
#pragma unroll
            for (int n = 0; n < 4; ++n)
                cr[n * 16] = acc[m][n][j];
        }
}

extern "C" void kernel_launch(void* const* d_in, const int* in_sizes, int n_in,
                              void* d_out, int out_size, void* d_ws, size_t ws_size,
                              hipStream_t stream) {
    const float* A  = (const float*)d_in[0];   // [8,4096,2048] fp32
    const float* Wt = (const float*)d_in[1];   // [2048,2048] fp32
    float* C = (float*)d_out;                  // [32768,2048] fp32

    const size_t needA = (size_t)M_DIM * K_DIM * 2;
    const size_t needW = (size_t)N_DIM * K_DIM * 2;

    if (ws_size >= needA + needW) {
        ushort* Abf = (ushort*)d_ws;
        ushort* Wbf = (ushort*)((char*)d_ws + needA);
        cvt_f32_bf16<<<dim3(2048), dim3(256), 0, stream>>>(A, Abf, (M_DIM * K_DIM) / 8);
        cvt_f32_bf16<<<dim3(2048), dim3(256), 0, stream>>>(Wt, Wbf, (N_DIM * K_DIM) / 8);
        agmm_32swz<<<dim3(NWG), dim3(512), 0, stream>>>(Abf, Wbf, C);
    } else {
        agmm_fused<<<dim3((M_DIM / 128) * (N_DIM / 128)), dim3(256), 0, stream>>>(A, Wt, C);
    }
}